// Round 7
// baseline (281.994 us; speedup 1.0000x reference)
//
#include <hip/hip_runtime.h>
#include <hip/hip_cooperative_groups.h>

namespace cg = cooperative_groups;

typedef _Float16 f16;
typedef _Float16 f16x8 __attribute__((ext_vector_type(8)));
typedef float    f32x4 __attribute__((ext_vector_type(4)));
typedef unsigned int u32x2 __attribute__((ext_vector_type(2)));

#define B_ 4
#define C_ 512
#define N_ 4096
#define M_ 64

__device__ __forceinline__ unsigned pk2(float a, float b) {
    union { f16 h[2]; unsigned u; } t;
    t.h[0] = (f16)a; t.h[1] = (f16)b;
    return t.u;
}

// ---------------------------------------------------------------------------
// Kernel W: convert [Wq;Wk;Wv] fp32 -> Wf[640][512] f16 (unchanged).
// ---------------------------------------------------------------------------
__global__ __launch_bounds__(256) void wcvt(
    const float* __restrict__ Wq, const float* __restrict__ Wk,
    const float* __restrict__ Wv, f16* __restrict__ Wf)
{
    const int e = (blockIdx.x * 256 + threadIdx.x) * 8;
    const float* src;
    int off;
    if (e < 32768)      { src = Wq; off = e; }
    else if (e < 65536) { src = Wk; off = e - 32768; }
    else                { src = Wv; off = e - 65536; }
    float4 a = *(const float4*)(src + off);
    float4 b = *(const float4*)(src + off + 4);
    f16x8 o;
    o[0]=(f16)a.x; o[1]=(f16)a.y; o[2]=(f16)a.z; o[3]=(f16)a.w;
    o[4]=(f16)b.x; o[5]=(f16)b.y; o[6]=(f16)b.z; o[7]=(f16)b.w;
    *(f16x8*)(Wf + e) = o;
}

// body for attn tile T: CBc = T&1 (compile-time), NBc = 1-CBc. (R6, verbatim)
#define ATTN_BODY(T, CBc, NBc) {                                              \
    f16x8 pbf[4][2];                                                          \
    _Pragma("unroll")                                                         \
    for (int is_ = 0; is_ < 4; ++is_)                                         \
        _Pragma("unroll")                                                     \
        for (int kh_ = 0; kh_ < 2; ++kh_)                                     \
            pbf[is_][kh_] = *(const f16x8*)(pbB + (CBc) * 8192 + rb[is_][kh_]); \
    f32x4 s0 = {}, s1 = {};                                                   \
    s0 = __builtin_amdgcn_mfma_f32_16x16x32_f16(akr[NBc][0], bqf[is0][0], s0, 0, 0, 0); \
    s0 = __builtin_amdgcn_mfma_f32_16x16x32_f16(akr[NBc][1], bqf[is0][1], s0, 0, 0, 0); \
    s1 = __builtin_amdgcn_mfma_f32_16x16x32_f16(akr[NBc][0], bqf[is1][0], s1, 0, 0, 0); \
    s1 = __builtin_amdgcn_mfma_f32_16x16x32_f16(akr[NBc][1], bqf[is1][1], s1, 0, 0, 0); \
    if ((T) + 2 < 64) {                                                       \
        const f16* kn_ = kp + (size_t)((T) + 2) * 4096;                       \
        akr[CBc][0] = *(const f16x8*)(kn_);                                   \
        akr[CBc][1] = *(const f16x8*)(kn_ + 512);                             \
    }                                                                         \
    {                                                                         \
        const f16* vt_ = vln + (size_t)((T) + 1) * 1024;                      \
        _Pragma("unroll")                                                     \
        for (int ct_ = 0; ct_ < 4; ++ct_) {                                   \
            vr[NBc][ct_]     = *(const f16x8*)(vt_ + (size_t)(cw + ct_) * 65536);       \
            vr[NBc][ct_ + 4] = *(const f16x8*)(vt_ + (size_t)(cw + ct_) * 65536 + 512); \
        }                                                                     \
    }                                                                         \
    {                                                                         \
        float p0 = __expf(s0[0] - m0), p1 = __expf(s0[1] - m0);               \
        float p2 = __expf(s0[2] - m0), p3 = __expf(s0[3] - m0);               \
        lp0 += (p0 + p1) + (p2 + p3);                                         \
        u32x2 pw = { pk2(p0, p1), pk2(p2, p3) };                              \
        *(u32x2*)(pbB + (NBc) * 8192 + wb0) = pw;                             \
    }                                                                         \
    {                                                                         \
        float q0 = __expf(s1[0] - m1), q1 = __expf(s1[1] - m1);               \
        float q2 = __expf(s1[2] - m1), q3 = __expf(s1[3] - m1);               \
        lp1 += (q0 + q1) + (q2 + q3);                                         \
        u32x2 pw = { pk2(q0, q1), pk2(q2, q3) };                              \
        *(u32x2*)(pbB + (NBc) * 8192 + wb1) = pw;                             \
    }                                                                         \
    __builtin_amdgcn_s_setprio(1);                                            \
    _Pragma("unroll")                                                         \
    for (int ct_ = 0; ct_ < 4; ++ct_)                                         \
        _Pragma("unroll")                                                     \
        for (int is_ = 0; is_ < 4; ++is_)                                     \
            acc[ct_][is_] = __builtin_amdgcn_mfma_f32_16x16x32_f16(           \
                vr[CBc][ct_], pbf[is_][0], acc[ct_][is_], 0, 0, 0);           \
    _Pragma("unroll")                                                         \
    for (int ct_ = 0; ct_ < 4; ++ct_)                                         \
        _Pragma("unroll")                                                     \
        for (int is_ = 0; is_ < 4; ++is_)                                     \
            acc[ct_][is_] = __builtin_amdgcn_mfma_f32_16x16x32_f16(           \
                vr[CBc][ct_ + 4], pbf[is_][1], acc[ct_][is_], 0, 0, 0);       \
    __builtin_amdgcn_s_setprio(0);                                            \
    asm volatile("s_waitcnt lgkmcnt(0)" ::: "memory");                        \
    __builtin_amdgcn_s_barrier();                                             \
    __builtin_amdgcn_sched_barrier(0);                                        \
}

// ---------------------------------------------------------------------------
// FUSED cooperative kernel: phase A = qkv4 (R6 body), grid.sync, phase B =
// attn (R6 body). Grid 256 x 512 thr, 1 block/CU (27.6KB LDS, VGPR<=256 via
// launch_bounds -> co-residency guaranteed). Single dispatch => producer
// phase finally visible in counters; inter-kernel launch gaps eliminated.
// ---------------------------------------------------------------------------
__global__ __launch_bounds__(512, 2) void fused(
    const f16* __restrict__ Wf, const float* __restrict__ x,
    const float* __restrict__ bq, const float* __restrict__ bk,
    const float* __restrict__ bv, const float* __restrict__ gamma,
    f16* __restrict__ qt, f16* __restrict__ ktf, f16* __restrict__ vf,
    float* __restrict__ out)
{
    __shared__ __align__(16) char smem[27648];   // A: 3*8192 ring + 640 bias
                                                 // B: 2*8192 P + mxs + lss
    const int tid  = threadIdx.x;
    const int w    = tid >> 6;
    const int lane = tid & 63;
    const int l15  = lane & 15;
    const int quad = lane >> 4;
    const int lin  = blockIdx.x;

    // ====================== phase A: qkv (R6 qkv4 body) ======================
    {
        const int n0   = (lin >> 2) * 64;
        const int b    = lin & 3;
        const int row0 = w * 80;
        char*  sH    = smem;                        // ring buffers [3][8192]
        float* sBias = (float*)(smem + 24576);      // 640 floats

        for (int e = tid; e < 640; e += 512)
            sBias[e] = (e < 64) ? bq[e] : (e < 128) ? bk[e - 64] : bv[e - 128];

        const int wbyte = (lane * 128 + w * 16) ^ ((lane & 7) << 4);
        int rbyte[4][2];
        #pragma unroll
        for (int nt = 0; nt < 4; ++nt)
            #pragma unroll
            for (int kh = 0; kh < 2; ++kh)
                rbyte[nt][kh] = ((nt * 16 + l15) * 128 + kh * 64 + quad * 16)
                                ^ ((l15 & 7) << 4);

        const float* xg = x + (size_t)b * (C_ * N_) + n0 + lane;
        const f16*   wp = Wf + (size_t)row0 * 512 + quad * 8;

        float gn[2][8];
        {
            float g0[8];
            #pragma unroll
            for (int u = 0; u < 8; ++u) g0[u] = xg[(size_t)(w * 8 + u) * N_];
            #pragma unroll
            for (int u = 0; u < 8; ++u) gn[1][u] = xg[(size_t)(64 + w * 8 + u) * N_];
            f16x8 h;
            #pragma unroll
            for (int u = 0; u < 8; ++u) h[u] = (f16)g0[u];
            *(f16x8*)(sH + wbyte) = h;
        }
        asm volatile("s_waitcnt lgkmcnt(0)" ::: "memory");
        __builtin_amdgcn_s_barrier();
        __builtin_amdgcn_sched_barrier(0);

        f32x4 acc[5][4] = {};

        #pragma unroll
        for (int t = 0; t < 8; ++t) {
            // W fragments issued first -> af-wait leaves x prefetch in flight
            f16x8 af[5][2];
            #pragma unroll
            for (int ot = 0; ot < 5; ++ot)
                #pragma unroll
                for (int kh = 0; kh < 2; ++kh)
                    af[ot][kh] = *(const f16x8*)(wp + (size_t)(ot * 16 + l15) * 512
                                                 + t * 64 + kh * 32);
            if (t + 2 < 8) {
                #pragma unroll
                for (int u = 0; u < 8; ++u)
                    gn[t & 1][u] = xg[(size_t)((t + 2) * 64 + w * 8 + u) * N_];
            }
            const char* sc = sH + (t % 3) * 8192;
            f16x8 bf[4][2];
            #pragma unroll
            for (int nt = 0; nt < 4; ++nt)
                #pragma unroll
                for (int kh = 0; kh < 2; ++kh)
                    bf[nt][kh] = *(const f16x8*)(sc + rbyte[nt][kh]);

            #pragma unroll
            for (int ot = 0; ot < 5; ++ot)
                #pragma unroll
                for (int kh = 0; kh < 2; ++kh)
                    #pragma unroll
                    for (int nt = 0; nt < 4; ++nt)
                        acc[ot][nt] = __builtin_amdgcn_mfma_f32_16x16x32_f16(
                            af[ot][kh], bf[nt][kh], acc[ot][nt], 0, 0, 0);

            if (t + 1 < 8) {
                f16x8 h;
                #pragma unroll
                for (int u = 0; u < 8; ++u) h[u] = (f16)gn[(t + 1) & 1][u];
                *(f16x8*)(sH + ((t + 1) % 3) * 8192 + wbyte) = h;
            }
            asm volatile("s_waitcnt lgkmcnt(0)" ::: "memory");
            __builtin_amdgcn_s_barrier();
            __builtin_amdgcn_sched_barrier(0);
        }

        // epilogue: bias + cast + scatter to validated layouts
        #pragma unroll
        for (int ot = 0; ot < 5; ++ot) {
            const int rowBase = row0 + ot * 16;
            const int rq = rowBase + quad * 4;
            #pragma unroll
            for (int nt = 0; nt < 4; ++nt) {
                const int n = n0 + nt * 16 + l15;
                union { f16 h[4]; unsigned long long u; } pkv;
                #pragma unroll
                for (int r = 0; r < 4; ++r)
                    pkv.h[r] = (f16)(acc[ot][nt][r] + sBias[rq + r]);
                if (rowBase < 64) {
                    *(unsigned long long*)(qt + ((size_t)(b * N_ + n)) * M_ + rq) = pkv.u;
                } else if (rowBase < 128) {
                    const int ol = rq - 64;
                    size_t idx = (((size_t)b * 256 + (n >> 4)) * 2 + (ol >> 5)) * 512
                               + (size_t)((((ol >> 3) & 3) * 16 + (n & 15)) * 8) + (ol & 7);
                    *(unsigned long long*)(ktf + idx) = pkv.u;
                } else {
                    const int c = rq - 128;
                    #pragma unroll
                    for (int r = 0; r < 4; ++r) {
                        size_t idx = ((size_t)b * (C_ * N_)) + (size_t)((c + r) >> 4) * 65536
                                   + (size_t)(n >> 6) * 1024 + (size_t)((n >> 5) & 1) * 512
                                   + (size_t)((((n >> 3) & 3) * 16 + ((c + r) & 15)) * 8) + (n & 7);
                        vf[idx] = pkv.h[r];
                    }
                }
            }
        }
    }

    cg::this_grid().sync();

    // ====================== phase B: attn (R6 body) =========================
    {
        char* pbB = smem;                                        // P dbuf 2x8192
        float (*mxs)[4][16] = (float (*)[4][16])(smem + 16384);  // 8x4x16
        float (*lss)[4][16] = (float (*)[4][16])(smem + 18432);  // 8x4x16

        const int jt   = w & 3;
        const int ish  = w >> 2;
        const int is0  = ish * 2, is1 = is0 + 1;

        const int b    = (lin & 7) >> 1;
        const int iblk = ((lin >> 3) << 1) | (lin & 1);
        const int i0   = iblk * 64;

        const f16* kln = ktf + (size_t)b * (N_ * M_) + lane * 8;
        const f16* vln = vf  + (size_t)b * (C_ * N_) + lane * 8;

        f16x8 bqf[4][2];
        #pragma unroll
        for (int is = 0; is < 4; ++is)
            #pragma unroll
            for (int kh = 0; kh < 2; ++kh)
                bqf[is][kh] = *(const f16x8*)(qt + ((size_t)(b * N_ + i0 + is * 16 + l15)) * M_
                                              + kh * 32 + quad * 8);

        // ---------------- pass 1: rowmax, j-range split across waves --------
        float mx[4];
        #pragma unroll
        for (int is = 0; is < 4; ++is) mx[is] = -3.0e38f;
        {
            const f16* kw = kln + (size_t)(w * 512) * 64;
            f16x8 akc[4][2];
            #pragma unroll
            for (int t = 0; t < 4; ++t)
                #pragma unroll
                for (int kh = 0; kh < 2; ++kh)
                    akc[t][kh] = *(const f16x8*)(kw + t * 1024 + kh * 512);

            #pragma unroll 2
            for (int jj = 0; jj < 512; jj += 64) {
                f16x8 akn[4][2];
                if (jj + 64 < 512) {
                    const f16* kn = kw + (size_t)(jj + 64) * 64;
                    #pragma unroll
                    for (int t = 0; t < 4; ++t)
                        #pragma unroll
                        for (int kh = 0; kh < 2; ++kh)
                            akn[t][kh] = *(const f16x8*)(kn + t * 1024 + kh * 512);
                }
                #pragma unroll
                for (int t = 0; t < 4; ++t) {
                    #pragma unroll
                    for (int is = 0; is < 4; ++is) {
                        f32x4 s = {};
                        s = __builtin_amdgcn_mfma_f32_16x16x32_f16(akc[t][0], bqf[is][0], s, 0, 0, 0);
                        s = __builtin_amdgcn_mfma_f32_16x16x32_f16(akc[t][1], bqf[is][1], s, 0, 0, 0);
                        mx[is] = fmaxf(mx[is], fmaxf(fmaxf(s[0], s[1]), fmaxf(s[2], s[3])));
                    }
                }
                #pragma unroll
                for (int t = 0; t < 4; ++t)
                    #pragma unroll
                    for (int kh = 0; kh < 2; ++kh)
                        akc[t][kh] = akn[t][kh];
            }
        }
        #pragma unroll
        for (int is = 0; is < 4; ++is) {
            mx[is] = fmaxf(mx[is], __shfl_xor(mx[is], 16, 64));
            mx[is] = fmaxf(mx[is], __shfl_xor(mx[is], 32, 64));
        }
        if (lane < 16) {
            #pragma unroll
            for (int is = 0; is < 4; ++is) mxs[w][is][lane] = mx[is];
        }
        __syncthreads();
        float m0 = -3.0e38f, m1 = -3.0e38f;
        #pragma unroll
        for (int w2 = 0; w2 < 8; ++w2) {
            m0 = fmaxf(m0, mxs[w2][is0][l15]);
            m1 = fmaxf(m1, mxs[w2][is1][l15]);
        }

        // ---------------- pass 2: counted-vmcnt pipelined P -> LDS -> PV ----
        f32x4 acc[4][4] = {};
        float lp0 = 0.f, lp1 = 0.f;

        const int swz = (l15 & 7) << 4;
        const int wb0 = ((is0 * 16 + l15) * 128 + (jt * 16 + quad * 4) * 2) ^ swz;
        const int wb1 = wb0 + 2048;
        int rb[4][2];
        #pragma unroll
        for (int is = 0; is < 4; ++is)
            #pragma unroll
            for (int kh = 0; kh < 2; ++kh)
                rb[is][kh] = ((is * 16 + l15) * 128 + kh * 64 + quad * 16) ^ swz;

        const f16* kp = kln + (size_t)(jt * 16) * 64;
        const int cw = w * 4;

        f16x8 akr[2][2];
        f16x8 vr[2][8];

        akr[0][0] = *(const f16x8*)(kp);
        akr[0][1] = *(const f16x8*)(kp + 512);
        {
            f32x4 s0 = {}, s1 = {};
            s0 = __builtin_amdgcn_mfma_f32_16x16x32_f16(akr[0][0], bqf[is0][0], s0, 0, 0, 0);
            s0 = __builtin_amdgcn_mfma_f32_16x16x32_f16(akr[0][1], bqf[is0][1], s0, 0, 0, 0);
            s1 = __builtin_amdgcn_mfma_f32_16x16x32_f16(akr[0][0], bqf[is1][0], s1, 0, 0, 0);
            s1 = __builtin_amdgcn_mfma_f32_16x16x32_f16(akr[0][1], bqf[is1][1], s1, 0, 0, 0);
            float p0 = __expf(s0[0] - m0), p1 = __expf(s0[1] - m0);
            float p2 = __expf(s0[2] - m0), p3 = __expf(s0[3] - m0);
            lp0 += (p0 + p1) + (p2 + p3);
            u32x2 pw0 = { pk2(p0, p1), pk2(p2, p3) };
            *(u32x2*)(pbB + wb0) = pw0;
            float q0 = __expf(s1[0] - m1), q1 = __expf(s1[1] - m1);
            float q2 = __expf(s1[2] - m1), q3 = __expf(s1[3] - m1);
            lp1 += (q0 + q1) + (q2 + q3);
            u32x2 pw1 = { pk2(q0, q1), pk2(q2, q3) };
            *(u32x2*)(pbB + wb1) = pw1;
        }
        akr[1][0] = *(const f16x8*)(kp + 4096);
        akr[1][1] = *(const f16x8*)(kp + 4096 + 512);
        #pragma unroll
        for (int ct = 0; ct < 4; ++ct) {
            vr[0][ct]     = *(const f16x8*)(vln + (size_t)(cw + ct) * 65536);
            vr[0][ct + 4] = *(const f16x8*)(vln + (size_t)(cw + ct) * 65536 + 512);
        }
        __syncthreads();

        for (int tt = 0; tt < 62; tt += 2) {
            ATTN_BODY(tt,     0, 1);
            ATTN_BODY(tt + 1, 1, 0);
        }
        ATTN_BODY(62, 0, 1);

        // epilogue: PV(63)
        {
            f16x8 pbf[4][2];
            #pragma unroll
            for (int is = 0; is < 4; ++is)
                #pragma unroll
                for (int kh = 0; kh < 2; ++kh)
                    pbf[is][kh] = *(const f16x8*)(pbB + 8192 + rb[is][kh]);
            #pragma unroll
            for (int ct = 0; ct < 4; ++ct)
                #pragma unroll
                for (int is = 0; is < 4; ++is)
                    acc[ct][is] = __builtin_amdgcn_mfma_f32_16x16x32_f16(vr[1][ct], pbf[is][0], acc[ct][is], 0, 0, 0);
            #pragma unroll
            for (int ct = 0; ct < 4; ++ct)
                #pragma unroll
                for (int is = 0; is < 4; ++is)
                    acc[ct][is] = __builtin_amdgcn_mfma_f32_16x16x32_f16(vr[1][ct + 4], pbf[is][1], acc[ct][is], 0, 0, 0);
        }

        lp0 += __shfl_xor(lp0, 16, 64);
        lp0 += __shfl_xor(lp0, 32, 64);
        lp1 += __shfl_xor(lp1, 16, 64);
        lp1 += __shfl_xor(lp1, 32, 64);
        if (lane < 16) { lss[w][is0][lane] = lp0; lss[w][is1][lane] = lp1; }
        __syncthreads();

        float linv[4];
        #pragma unroll
        for (int is = 0; is < 4; ++is) {
            const int wb = (is >> 1) * 4;
            float l = (lss[wb + 0][is][l15] + lss[wb + 1][is][l15])
                    + (lss[wb + 2][is][l15] + lss[wb + 3][is][l15]);
            linv[is] = 1.0f / l;
        }

        const float g = gamma[0];
        #pragma unroll
        for (int is = 0; is < 4; ++is) {
            const int i = i0 + is * 16 + l15;
            #pragma unroll
            for (int ct = 0; ct < 4; ++ct) {
                #pragma unroll
                for (int r = 0; r < 4; ++r) {
                    const int c = w * 64 + ct * 16 + quad * 4 + r;
                    const size_t idx = ((size_t)(b * C_ + c)) * N_ + i;
                    out[idx] = g * (acc[ct][is][r] * linv[is]) + x[idx];
                }
            }
        }
    }
}

// ---------------------------------------------------------------------------
extern "C" void kernel_launch(void* const* d_in, const int* in_sizes, int n_in,
                              void* d_out, int out_size, void* d_ws, size_t ws_size,
                              hipStream_t stream)
{
    const float* x     = (const float*)d_in[0];
    const float* Wq    = (const float*)d_in[1];
    const float* bq    = (const float*)d_in[2];
    const float* Wk    = (const float*)d_in[3];
    const float* bk    = (const float*)d_in[4];
    const float* Wv    = (const float*)d_in[5];
    const float* bv    = (const float*)d_in[6];
    const float* gamma = (const float*)d_in[7];
    float* out = (float*)d_out;

    char* ws = (char*)d_ws;
    f16* qt  = (f16*)ws;                                   // B*N*M   ( 2 MB)
    f16* ktf = qt + (size_t)B_ * N_ * M_;                  // B*N*M   ( 2 MB)
    f16* vf  = ktf + (size_t)B_ * N_ * M_;                 // B*C*N   (16 MB)
    f16* Wf  = vf + (size_t)B_ * C_ * N_;                  // 640*512 (0.6 MB)

    wcvt<<<dim3(160), 256, 0, stream>>>(Wq, Wk, Wv, Wf);

    const f16* WfC = Wf;
    void* args[] = { (void*)&WfC, (void*)&x, (void*)&bq, (void*)&bk, (void*)&bv,
                     (void*)&gamma, (void*)&qt, (void*)&ktf, (void*)&vf, (void*)&out };
    hipLaunchCooperativeKernel((void*)fused, dim3(256), dim3(512), args, 0, stream);
}

// Round 8
// 224.760 us; speedup vs baseline: 1.2546x; 1.2546x over previous
//
#include <hip/hip_runtime.h>

typedef _Float16 f16;
typedef _Float16 f16x8 __attribute__((ext_vector_type(8)));
typedef float    f32x4 __attribute__((ext_vector_type(4)));
typedef unsigned int u32x2 __attribute__((ext_vector_type(2)));

#define B_ 4
#define C_ 512
#define N_ 4096
#define M_ 64

// lgkm-only barrier, NO memory clobber (a "memory" clobber forces the
// backend to insert s_waitcnt vmcnt(0) before the asm — the exact drain
// we must avoid). sched_barrier(0) on both sides pins ds op ordering
// around the barrier (rule #18).
#define LGKM_BARRIER()                                        \
    __builtin_amdgcn_sched_barrier(0);                        \
    asm volatile("s_waitcnt lgkmcnt(0)");                     \
    __builtin_amdgcn_s_barrier();                             \
    __builtin_amdgcn_sched_barrier(0);

__device__ __forceinline__ unsigned pk2(float a, float b) {
    union { f16 h[2]; unsigned u; } t;
    t.h[0] = (f16)a; t.h[1] = (f16)b;
    return t.u;
}

// ---------------------------------------------------------------------------
// Kernel W: convert [Wq;Wk;Wv] fp32 -> Wf[640][512] f16 (unchanged).
// ---------------------------------------------------------------------------
__global__ __launch_bounds__(256) void wcvt(
    const float* __restrict__ Wq, const float* __restrict__ Wk,
    const float* __restrict__ Wv, f16* __restrict__ Wf)
{
    const int e = (blockIdx.x * 256 + threadIdx.x) * 8;
    const float* src;
    int off;
    if (e < 32768)      { src = Wq; off = e; }
    else if (e < 65536) { src = Wk; off = e - 32768; }
    else                { src = Wv; off = e - 65536; }
    float4 a = *(const float4*)(src + off);
    float4 b = *(const float4*)(src + off + 4);
    f16x8 o;
    o[0]=(f16)a.x; o[1]=(f16)a.y; o[2]=(f16)a.z; o[3]=(f16)a.w;
    o[4]=(f16)b.x; o[5]=(f16)b.y; o[6]=(f16)b.z; o[7]=(f16)b.w;
    *(f16x8*)(Wf + e) = o;
}

// ---------------------------------------------------------------------------
// Kernel A ("qkv4", R6 structure + clobber-free barriers): 3-deep LDS ring,
// x prefetched 2 chunks ahead; W loads issued first each chunk so the MFMA
// af-wait leaves the x prefetch outstanding; barriers drain LDS only —
// global loads now genuinely ride across.
// ---------------------------------------------------------------------------
__global__ __launch_bounds__(512, 2) void qkv4(
    const f16* __restrict__ Wf, const float* __restrict__ x,
    const float* __restrict__ bq, const float* __restrict__ bk,
    const float* __restrict__ bv,
    f16* __restrict__ qt, f16* __restrict__ ktf, f16* __restrict__ vf)
{
    __shared__ __align__(16) char sH[3][8192];   // ring: 64n x 64c f16, swizzled
    __shared__ float sBias[640];

    const int tid  = threadIdx.x;
    const int w    = tid >> 6;
    const int lane = tid & 63;
    const int l15  = lane & 15;
    const int quad = lane >> 4;
    const int n0   = blockIdx.x * 64;
    const int b    = blockIdx.y;
    const int row0 = w * 80;

    for (int e = tid; e < 640; e += 512)
        sBias[e] = (e < 64) ? bq[e] : (e < 128) ? bk[e - 64] : bv[e - 128];

    const int wbyte = (lane * 128 + w * 16) ^ ((lane & 7) << 4);
    int rbyte[4][2];
    #pragma unroll
    for (int nt = 0; nt < 4; ++nt)
        #pragma unroll
        for (int kh = 0; kh < 2; ++kh)
            rbyte[nt][kh] = ((nt * 16 + l15) * 128 + kh * 64 + quad * 16)
                            ^ ((l15 & 7) << 4);

    const float* xg = x + (size_t)b * (C_ * N_) + n0 + lane;
    const f16*   wp = Wf + (size_t)row0 * 512 + quad * 8;

    float gn[2][8];
    {
        float g0[8];
        #pragma unroll
        for (int u = 0; u < 8; ++u) g0[u] = xg[(size_t)(w * 8 + u) * N_];
        #pragma unroll
        for (int u = 0; u < 8; ++u) gn[1][u] = xg[(size_t)(64 + w * 8 + u) * N_];
        f16x8 h;
        #pragma unroll
        for (int u = 0; u < 8; ++u) h[u] = (f16)g0[u];
        *(f16x8*)(&sH[0][0] + wbyte) = h;
    }
    LGKM_BARRIER();

    f32x4 acc[5][4] = {};

    #pragma unroll
    for (int t = 0; t < 8; ++t) {
        // W fragments issued first -> af-wait leaves x prefetch in flight
        f16x8 af[5][2];
        #pragma unroll
        for (int ot = 0; ot < 5; ++ot)
            #pragma unroll
            for (int kh = 0; kh < 2; ++kh)
                af[ot][kh] = *(const f16x8*)(wp + (size_t)(ot * 16 + l15) * 512
                                             + t * 64 + kh * 32);
        if (t + 2 < 8) {
            #pragma unroll
            for (int u = 0; u < 8; ++u)
                gn[t & 1][u] = xg[(size_t)((t + 2) * 64 + w * 8 + u) * N_];
        }
        const char* sc = &sH[t % 3][0];
        f16x8 bf[4][2];
        #pragma unroll
        for (int nt = 0; nt < 4; ++nt)
            #pragma unroll
            for (int kh = 0; kh < 2; ++kh)
                bf[nt][kh] = *(const f16x8*)(sc + rbyte[nt][kh]);

        #pragma unroll
        for (int ot = 0; ot < 5; ++ot)
            #pragma unroll
            for (int kh = 0; kh < 2; ++kh)
                #pragma unroll
                for (int nt = 0; nt < 4; ++nt)
                    acc[ot][nt] = __builtin_amdgcn_mfma_f32_16x16x32_f16(
                        af[ot][kh], bf[nt][kh], acc[ot][nt], 0, 0, 0);

        if (t + 1 < 8) {
            f16x8 h;
            #pragma unroll
            for (int u = 0; u < 8; ++u) h[u] = (f16)gn[(t + 1) & 1][u];
            *(f16x8*)(&sH[(t + 1) % 3][0] + wbyte) = h;
        }
        LGKM_BARRIER();
    }

    // epilogue: bias + cast + scatter to validated layouts
    #pragma unroll
    for (int ot = 0; ot < 5; ++ot) {
        const int rowBase = row0 + ot * 16;
        const int rq = rowBase + quad * 4;
        #pragma unroll
        for (int nt = 0; nt < 4; ++nt) {
            const int n = n0 + nt * 16 + l15;
            union { f16 h[4]; unsigned long long u; } pkv;
            #pragma unroll
            for (int r = 0; r < 4; ++r)
                pkv.h[r] = (f16)(acc[ot][nt][r] + sBias[rq + r]);
            if (rowBase < 64) {
                *(unsigned long long*)(qt + ((size_t)(b * N_ + n)) * M_ + rq) = pkv.u;
            } else if (rowBase < 128) {
                const int ol = rq - 64;
                size_t idx = (((size_t)b * 256 + (n >> 4)) * 2 + (ol >> 5)) * 512
                           + (size_t)((((ol >> 3) & 3) * 16 + (n & 15)) * 8) + (ol & 7);
                *(unsigned long long*)(ktf + idx) = pkv.u;
            } else {
                const int c = rq - 128;
                #pragma unroll
                for (int r = 0; r < 4; ++r) {
                    size_t idx = ((size_t)b * (C_ * N_)) + (size_t)((c + r) >> 4) * 65536
                               + (size_t)(n >> 6) * 1024 + (size_t)((n >> 5) & 1) * 512
                               + (size_t)((((n >> 3) & 3) * 16 + ((c + r) & 15)) * 8) + (n & 7);
                    vf[idx] = pkv.h[r];
                }
            }
        }
    }
}

// body for attn tile T: CBc = T&1 (compile-time), NBc = 1-CBc.
#define ATTN_BODY(T, CBc, NBc) {                                              \
    f16x8 pbf[4][2];                                                          \
    _Pragma("unroll")                                                         \
    for (int is_ = 0; is_ < 4; ++is_)                                         \
        _Pragma("unroll")                                                     \
        for (int kh_ = 0; kh_ < 2; ++kh_)                                     \
            pbf[is_][kh_] = *(const f16x8*)(pbB + (CBc) * 8192 + rb[is_][kh_]); \
    f32x4 s0 = {}, s1 = {};                                                   \
    s0 = __builtin_amdgcn_mfma_f32_16x16x32_f16(akr[NBc][0], bqf[is0][0], s0, 0, 0, 0); \
    s0 = __builtin_amdgcn_mfma_f32_16x16x32_f16(akr[NBc][1], bqf[is0][1], s0, 0, 0, 0); \
    s1 = __builtin_amdgcn_mfma_f32_16x16x32_f16(akr[NBc][0], bqf[is1][0], s1, 0, 0, 0); \
    s1 = __builtin_amdgcn_mfma_f32_16x16x32_f16(akr[NBc][1], bqf[is1][1], s1, 0, 0, 0); \
    if ((T) + 2 < 64) {                                                       \
        const f16* kn_ = kp + (size_t)((T) + 2) * 4096;                       \
        akr[CBc][0] = *(const f16x8*)(kn_);                                   \
        akr[CBc][1] = *(const f16x8*)(kn_ + 512);                             \
    }                                                                         \
    {                                                                         \
        const f16* vt_ = vln + (size_t)((T) + 1) * 1024;                      \
        _Pragma("unroll")                                                     \
        for (int ct_ = 0; ct_ < 4; ++ct_) {                                   \
            vr[NBc][ct_]     = *(const f16x8*)(vt_ + (size_t)(cw + ct_) * 65536);       \
            vr[NBc][ct_ + 4] = *(const f16x8*)(vt_ + (size_t)(cw + ct_) * 65536 + 512); \
        }                                                                     \
    }                                                                         \
    {                                                                         \
        float p0 = __expf(s0[0] - m0), p1 = __expf(s0[1] - m0);               \
        float p2 = __expf(s0[2] - m0), p3 = __expf(s0[3] - m0);               \
        lp0 += (p0 + p1) + (p2 + p3);                                         \
        u32x2 pw = { pk2(p0, p1), pk2(p2, p3) };                              \
        *(u32x2*)(pbB + (NBc) * 8192 + wb0) = pw;                             \
    }                                                                         \
    {                                                                         \
        float q0 = __expf(s1[0] - m1), q1 = __expf(s1[1] - m1);               \
        float q2 = __expf(s1[2] - m1), q3 = __expf(s1[3] - m1);               \
        lp1 += (q0 + q1) + (q2 + q3);                                         \
        u32x2 pw = { pk2(q0, q1), pk2(q2, q3) };                              \
        *(u32x2*)(pbB + (NBc) * 8192 + wb1) = pw;                             \
    }                                                                         \
    __builtin_amdgcn_s_setprio(1);                                            \
    _Pragma("unroll")                                                         \
    for (int ct_ = 0; ct_ < 4; ++ct_)                                         \
        _Pragma("unroll")                                                     \
        for (int is_ = 0; is_ < 4; ++is_)                                     \
            acc[ct_][is_] = __builtin_amdgcn_mfma_f32_16x16x32_f16(           \
                vr[CBc][ct_], pbf[is_][0], acc[ct_][is_], 0, 0, 0);           \
    _Pragma("unroll")                                                         \
    for (int ct_ = 0; ct_ < 4; ++ct_)                                         \
        _Pragma("unroll")                                                     \
        for (int is_ = 0; is_ < 4; ++is_)                                     \
            acc[ct_][is_] = __builtin_amdgcn_mfma_f32_16x16x32_f16(           \
                vr[CBc][ct_ + 4], pbf[is_][1], acc[ct_][is_], 0, 0, 0);       \
    __builtin_amdgcn_s_setprio(0);                                            \
    LGKM_BARRIER();                                                           \
}

// ---------------------------------------------------------------------------
// Kernel B: attn (R6 structure + clobber-free barriers): V/K register
// prefetch now truly rides across the per-tile barrier.
// ---------------------------------------------------------------------------
__global__ __launch_bounds__(512, 2) void attn(
    const f16* __restrict__ qt, const f16* __restrict__ ktf,
    const f16* __restrict__ vf, const float* __restrict__ x,
    const float* __restrict__ gamma, float* __restrict__ out)
{
    __shared__ __align__(16) char Pb[2][8192];   // P: 64 i x 64 j f16, dbuf
    __shared__ float mxs[8][4][16];
    __shared__ float lss[8][4][16];

    const int tid  = threadIdx.x;
    const int w    = tid >> 6;                  // 0..7
    const int lane = tid & 63;
    const int l15  = lane & 15;
    const int quad = lane >> 4;
    const int jt   = w & 3;
    const int ish  = w >> 2;
    const int is0  = ish * 2, is1 = is0 + 1;

    const int lin  = blockIdx.x;                // 0..255
    const int b    = (lin & 7) >> 1;            // XCD-pinned batch
    const int iblk = ((lin >> 3) << 1) | (lin & 1);
    const int i0   = iblk * 64;

    const f16* kln = ktf + (size_t)b * (N_ * M_) + lane * 8;
    const f16* vln = vf  + (size_t)b * (C_ * N_) + lane * 8;

    f16x8 bqf[4][2];
    #pragma unroll
    for (int is = 0; is < 4; ++is)
        #pragma unroll
        for (int kh = 0; kh < 2; ++kh)
            bqf[is][kh] = *(const f16x8*)(qt + ((size_t)(b * N_ + i0 + is * 16 + l15)) * M_
                                          + kh * 32 + quad * 8);

    // ---------------- pass 1: rowmax, j-range split across waves ----------
    float mx[4];
    #pragma unroll
    for (int is = 0; is < 4; ++is) mx[is] = -3.0e38f;
    {
        const f16* kw = kln + (size_t)(w * 512) * 64;
        f16x8 akc[4][2];
        #pragma unroll
        for (int t = 0; t < 4; ++t)
            #pragma unroll
            for (int kh = 0; kh < 2; ++kh)
                akc[t][kh] = *(const f16x8*)(kw + t * 1024 + kh * 512);

        #pragma unroll 2
        for (int jj = 0; jj < 512; jj += 64) {
            f16x8 akn[4][2];
            if (jj + 64 < 512) {
                const f16* kn = kw + (size_t)(jj + 64) * 64;
                #pragma unroll
                for (int t = 0; t < 4; ++t)
                    #pragma unroll
                    for (int kh = 0; kh < 2; ++kh)
                        akn[t][kh] = *(const f16x8*)(kn + t * 1024 + kh * 512);
            }
            #pragma unroll
            for (int t = 0; t < 4; ++t) {
                #pragma unroll
                for (int is = 0; is < 4; ++is) {
                    f32x4 s = {};
                    s = __builtin_amdgcn_mfma_f32_16x16x32_f16(akc[t][0], bqf[is][0], s, 0, 0, 0);
                    s = __builtin_amdgcn_mfma_f32_16x16x32_f16(akc[t][1], bqf[is][1], s, 0, 0, 0);
                    mx[is] = fmaxf(mx[is], fmaxf(fmaxf(s[0], s[1]), fmaxf(s[2], s[3])));
                }
            }
            #pragma unroll
            for (int t = 0; t < 4; ++t)
                #pragma unroll
                for (int kh = 0; kh < 2; ++kh)
                    akc[t][kh] = akn[t][kh];
        }
    }
    #pragma unroll
    for (int is = 0; is < 4; ++is) {
        mx[is] = fmaxf(mx[is], __shfl_xor(mx[is], 16, 64));
        mx[is] = fmaxf(mx[is], __shfl_xor(mx[is], 32, 64));
    }
    if (lane < 16) {
        #pragma unroll
        for (int is = 0; is < 4; ++is) mxs[w][is][lane] = mx[is];
    }
    __syncthreads();
    float m0 = -3.0e38f, m1 = -3.0e38f;
    #pragma unroll
    for (int w2 = 0; w2 < 8; ++w2) {
        m0 = fmaxf(m0, mxs[w2][is0][l15]);
        m1 = fmaxf(m1, mxs[w2][is1][l15]);
    }

    // ---------------- pass 2: pipelined P -> LDS -> PV ---------------------
    f32x4 acc[4][4] = {};
    float lp0 = 0.f, lp1 = 0.f;

    char* pbB = (char*)&Pb[0][0];
    const int swz = (l15 & 7) << 4;
    const int wb0 = ((is0 * 16 + l15) * 128 + (jt * 16 + quad * 4) * 2) ^ swz;
    const int wb1 = wb0 + 2048;
    int rb[4][2];
    #pragma unroll
    for (int is = 0; is < 4; ++is)
        #pragma unroll
        for (int kh = 0; kh < 2; ++kh)
            rb[is][kh] = ((is * 16 + l15) * 128 + kh * 64 + quad * 16) ^ swz;

    const f16* kp = kln + (size_t)(jt * 16) * 64;
    const int cw = w * 4;

    f16x8 akr[2][2];
    f16x8 vr[2][8];

    akr[0][0] = *(const f16x8*)(kp);
    akr[0][1] = *(const f16x8*)(kp + 512);
    {
        f32x4 s0 = {}, s1 = {};
        s0 = __builtin_amdgcn_mfma_f32_16x16x32_f16(akr[0][0], bqf[is0][0], s0, 0, 0, 0);
        s0 = __builtin_amdgcn_mfma_f32_16x16x32_f16(akr[0][1], bqf[is0][1], s0, 0, 0, 0);
        s1 = __builtin_amdgcn_mfma_f32_16x16x32_f16(akr[0][0], bqf[is1][0], s1, 0, 0, 0);
        s1 = __builtin_amdgcn_mfma_f32_16x16x32_f16(akr[0][1], bqf[is1][1], s1, 0, 0, 0);
        float p0 = __expf(s0[0] - m0), p1 = __expf(s0[1] - m0);
        float p2 = __expf(s0[2] - m0), p3 = __expf(s0[3] - m0);
        lp0 += (p0 + p1) + (p2 + p3);
        u32x2 pw0 = { pk2(p0, p1), pk2(p2, p3) };
        *(u32x2*)(pbB + wb0) = pw0;
        float q0 = __expf(s1[0] - m1), q1 = __expf(s1[1] - m1);
        float q2 = __expf(s1[2] - m1), q3 = __expf(s1[3] - m1);
        lp1 += (q0 + q1) + (q2 + q3);
        u32x2 pw1 = { pk2(q0, q1), pk2(q2, q3) };
        *(u32x2*)(pbB + wb1) = pw1;
    }
    akr[1][0] = *(const f16x8*)(kp + 4096);
    akr[1][1] = *(const f16x8*)(kp + 4096 + 512);
    #pragma unroll
    for (int ct = 0; ct < 4; ++ct) {
        vr[0][ct]     = *(const f16x8*)(vln + (size_t)(cw + ct) * 65536);
        vr[0][ct + 4] = *(const f16x8*)(vln + (size_t)(cw + ct) * 65536 + 512);
    }
    __syncthreads();

    for (int tt = 0; tt < 62; tt += 2) {
        ATTN_BODY(tt,     0, 1);
        ATTN_BODY(tt + 1, 1, 0);
    }
    ATTN_BODY(62, 0, 1);

    // epilogue: PV(63) — P in buf1 (written at T=62), V in vr[1]
    {
        f16x8 pbf[4][2];
        #pragma unroll
        for (int is = 0; is < 4; ++is)
            #pragma unroll
            for (int kh = 0; kh < 2; ++kh)
                pbf[is][kh] = *(const f16x8*)(pbB + 8192 + rb[is][kh]);
        #pragma unroll
        for (int ct = 0; ct < 4; ++ct)
            #pragma unroll
            for (int is = 0; is < 4; ++is)
                acc[ct][is] = __builtin_amdgcn_mfma_f32_16x16x32_f16(vr[1][ct], pbf[is][0], acc[ct][is], 0, 0, 0);
        #pragma unroll
        for (int ct = 0; ct < 4; ++ct)
            #pragma unroll
            for (int is = 0; is < 4; ++is)
                acc[ct][is] = __builtin_amdgcn_mfma_f32_16x16x32_f16(vr[1][ct + 4], pbf[is][1], acc[ct][is], 0, 0, 0);
    }

    // ---------------- l combine + epilogue ---------------------------------
    lp0 += __shfl_xor(lp0, 16, 64);
    lp0 += __shfl_xor(lp0, 32, 64);
    lp1 += __shfl_xor(lp1, 16, 64);
    lp1 += __shfl_xor(lp1, 32, 64);
    if (lane < 16) { lss[w][is0][lane] = lp0; lss[w][is1][lane] = lp1; }
    __syncthreads();

    float linv[4];
    #pragma unroll
    for (int is = 0; is < 4; ++is) {
        const int wb = (is >> 1) * 4;
        float l = (lss[wb + 0][is][l15] + lss[wb + 1][is][l15])
                + (lss[wb + 2][is][l15] + lss[wb + 3][is][l15]);
        linv[is] = 1.0f / l;
    }

    const float g = gamma[0];
    #pragma unroll
    for (int is = 0; is < 4; ++is) {
        const int i = i0 + is * 16 + l15;
        #pragma unroll
        for (int ct = 0; ct < 4; ++ct) {
            #pragma unroll
            for (int r = 0; r < 4; ++r) {
                const int c = w * 64 + ct * 16 + quad * 4 + r;
                const size_t idx = ((size_t)(b * C_ + c)) * N_ + i;
                out[idx] = g * (acc[ct][is][r] * linv[is]) + x[idx];
            }
        }
    }
}

// ---------------------------------------------------------------------------
extern "C" void kernel_launch(void* const* d_in, const int* in_sizes, int n_in,
                              void* d_out, int out_size, void* d_ws, size_t ws_size,
                              hipStream_t stream)
{
    const float* x     = (const float*)d_in[0];
    const float* Wq    = (const float*)d_in[1];
    const float* bq    = (const float*)d_in[2];
    const float* Wk    = (const float*)d_in[3];
    const float* bk    = (const float*)d_in[4];
    const float* Wv    = (const float*)d_in[5];
    const float* bv    = (const float*)d_in[6];
    const float* gamma = (const float*)d_in[7];
    float* out = (float*)d_out;

    char* ws = (char*)d_ws;
    f16* qt  = (f16*)ws;                                   // B*N*M   ( 2 MB)
    f16* ktf = qt + (size_t)B_ * N_ * M_;                  // B*N*M   ( 2 MB)
    f16* vf  = ktf + (size_t)B_ * N_ * M_;                 // B*C*N   (16 MB)
    f16* Wf  = vf + (size_t)B_ * C_ * N_;                  // 640*512 (0.6 MB)

    wcvt<<<dim3(160), 256, 0, stream>>>(Wq, Wk, Wv, Wf);
    qkv4<<<dim3(N_ / 64, B_), 512, 0, stream>>>(Wf, x, bq, bk, bv, qt, ktf, vf);
    attn<<<dim3(256), 512, 0, stream>>>(qt, ktf, vf, x, gamma, out);
}

// Round 9
// 219.434 us; speedup vs baseline: 1.2851x; 1.0243x over previous
//
#include <hip/hip_runtime.h>

typedef _Float16 f16;
typedef _Float16 f16x8 __attribute__((ext_vector_type(8)));
typedef float    f32x4 __attribute__((ext_vector_type(4)));
typedef unsigned int u32x2 __attribute__((ext_vector_type(2)));

#define B_ 4
#define C_ 512
#define N_ 4096
#define M_ 64

// lgkm-only barrier, no memory clobber (clobber forces a vmcnt(0) drain).
#define LGKM_BARRIER()                                        \
    __builtin_amdgcn_sched_barrier(0);                        \
    asm volatile("s_waitcnt lgkmcnt(0)");                     \
    __builtin_amdgcn_s_barrier();                             \
    __builtin_amdgcn_sched_barrier(0);

__device__ __forceinline__ unsigned pk2(float a, float b) {
    union { f16 h[2]; unsigned u; } t;
    t.h[0] = (f16)a; t.h[1] = (f16)b;
    return t.u;
}

// ---------------------------------------------------------------------------
// Kernel W: convert [Wq;Wk;Wv] fp32 -> Wf[640][512] f16 (unchanged).
// ---------------------------------------------------------------------------
__global__ __launch_bounds__(256) void wcvt(
    const float* __restrict__ Wq, const float* __restrict__ Wk,
    const float* __restrict__ Wv, f16* __restrict__ Wf)
{
    const int e = (blockIdx.x * 256 + threadIdx.x) * 8;
    const float* src;
    int off;
    if (e < 32768)      { src = Wq; off = e; }
    else if (e < 65536) { src = Wk; off = e - 32768; }
    else                { src = Wv; off = e - 65536; }
    float4 a = *(const float4*)(src + off);
    float4 b = *(const float4*)(src + off + 4);
    f16x8 o;
    o[0]=(f16)a.x; o[1]=(f16)a.y; o[2]=(f16)a.z; o[3]=(f16)a.w;
    o[4]=(f16)b.x; o[5]=(f16)b.y; o[6]=(f16)b.z; o[7]=(f16)b.w;
    *(f16x8*)(Wf + e) = o;
}

// ---------------------------------------------------------------------------
// Kernel A (R9 "qkv5"): SINGLE-BARRIER producer.
//  Whole x tile (64n x 512c) staged as f16 into 64KB swizzled LDS via 8
//  independent per-thread stages (disjoint slots -> NO inter-stage barriers),
//  then ONE __syncthreads, then all 320 MFMA with compiler-counted waits.
//  All 8 per-chunk barriers + drains of R6-R8 are gone.
//  amdgpu_waves_per_eu(2,2): 512-thr block @ grid 256 = 2 waves/SIMD always;
//  pinning it frees the allocator to 256 VGPR (was heuristically 128 ->
//  spilling the ~190-reg live set to scratch).
// ---------------------------------------------------------------------------
__global__ __launch_bounds__(512) __attribute__((amdgpu_waves_per_eu(2, 2)))
void qkv5(
    const f16* __restrict__ Wf, const float* __restrict__ x,
    const float* __restrict__ bq, const float* __restrict__ bk,
    const float* __restrict__ bv,
    f16* __restrict__ qt, f16* __restrict__ ktf, f16* __restrict__ vf)
{
    __shared__ __align__(16) char sX[65536];   // [64n][512c] f16, swizzled
    __shared__ float sBias[640];

    const int tid  = threadIdx.x;
    const int w    = tid >> 6;
    const int lane = tid & 63;
    const int l15  = lane & 15;
    const int quad = lane >> 4;
    const int n0   = blockIdx.x * 64;
    const int b    = blockIdx.y;
    const int row0 = w * 80;

    for (int e = tid; e < 640; e += 512)
        sBias[e] = (e < 64) ? bq[e] : (e < 128) ? bk[e - 64] : bv[e - 128];

    // stage: thread covers n = lane, c = s*64 + w*8 + u  (u=0..7, s=0..7)
    const float* xg = x + (size_t)b * (C_ * N_) + n0 + lane;
    #pragma unroll
    for (int s = 0; s < 8; ++s) {
        float g[8];
        #pragma unroll
        for (int u = 0; u < 8; ++u)
            g[u] = xg[(size_t)(s * 64 + w * 8 + u) * N_];
        f16x8 h;
        #pragma unroll
        for (int u = 0; u < 8; ++u) h[u] = (f16)g[u];
        const int c0 = s * 64 + w * 8;
        *(f16x8*)(sX + ((lane * 1024 + c0 * 2) ^ ((lane & 7) << 4))) = h;
    }
    __syncthreads();   // the ONLY barrier

    f32x4 acc[5][4] = {};
    const f16* wp = Wf + (size_t)row0 * 512 + quad * 8;

    #pragma unroll
    for (int t = 0; t < 8; ++t) {
        f16x8 af[5][2];
        #pragma unroll
        for (int ot = 0; ot < 5; ++ot)
            #pragma unroll
            for (int kh = 0; kh < 2; ++kh)
                af[ot][kh] = *(const f16x8*)(wp + (size_t)(ot * 16 + l15) * 512
                                             + t * 64 + kh * 32);
        f16x8 bf[4][2];
        #pragma unroll
        for (int nt = 0; nt < 4; ++nt)
            #pragma unroll
            for (int kh = 0; kh < 2; ++kh) {
                const int byte = ((nt * 16 + l15) * 1024 + t * 128 + kh * 64 + quad * 16)
                                 ^ ((l15 & 7) << 4);
                bf[nt][kh] = *(const f16x8*)(sX + byte);
            }

        #pragma unroll
        for (int ot = 0; ot < 5; ++ot)
            #pragma unroll
            for (int kh = 0; kh < 2; ++kh)
                #pragma unroll
                for (int nt = 0; nt < 4; ++nt)
                    acc[ot][nt] = __builtin_amdgcn_mfma_f32_16x16x32_f16(
                        af[ot][kh], bf[nt][kh], acc[ot][nt], 0, 0, 0);
    }

    // epilogue: bias + cast + scatter to validated layouts (unchanged)
    #pragma unroll
    for (int ot = 0; ot < 5; ++ot) {
        const int rowBase = row0 + ot * 16;
        const int rq = rowBase + quad * 4;
        #pragma unroll
        for (int nt = 0; nt < 4; ++nt) {
            const int n = n0 + nt * 16 + l15;
            union { f16 h[4]; unsigned long long u; } pkv;
            #pragma unroll
            for (int r = 0; r < 4; ++r)
                pkv.h[r] = (f16)(acc[ot][nt][r] + sBias[rq + r]);
            if (rowBase < 64) {
                *(unsigned long long*)(qt + ((size_t)(b * N_ + n)) * M_ + rq) = pkv.u;
            } else if (rowBase < 128) {
                const int ol = rq - 64;
                size_t idx = (((size_t)b * 256 + (n >> 4)) * 2 + (ol >> 5)) * 512
                           + (size_t)((((ol >> 3) & 3) * 16 + (n & 15)) * 8) + (ol & 7);
                *(unsigned long long*)(ktf + idx) = pkv.u;
            } else {
                const int c = rq - 128;
                #pragma unroll
                for (int r = 0; r < 4; ++r) {
                    size_t idx = ((size_t)b * (C_ * N_)) + (size_t)((c + r) >> 4) * 65536
                               + (size_t)(n >> 6) * 1024 + (size_t)((n >> 5) & 1) * 512
                               + (size_t)((((n >> 3) & 3) * 16 + ((c + r) & 15)) * 8) + (n & 7);
                    vf[idx] = pkv.h[r];
                }
            }
        }
    }
}

// body for attn tile T: CBc = T&1 (compile-time), NBc = 1-CBc.
#define ATTN_BODY(T, CBc, NBc) {                                              \
    f16x8 pbf[4][2];                                                          \
    _Pragma("unroll")                                                         \
    for (int is_ = 0; is_ < 4; ++is_)                                         \
        _Pragma("unroll")                                                     \
        for (int kh_ = 0; kh_ < 2; ++kh_)                                     \
            pbf[is_][kh_] = *(const f16x8*)(pbB + (CBc) * 8192 + rb[is_][kh_]); \
    f32x4 s0 = {}, s1 = {};                                                   \
    s0 = __builtin_amdgcn_mfma_f32_16x16x32_f16(akr[NBc][0], bqf[is0][0], s0, 0, 0, 0); \
    s0 = __builtin_amdgcn_mfma_f32_16x16x32_f16(akr[NBc][1], bqf[is0][1], s0, 0, 0, 0); \
    s1 = __builtin_amdgcn_mfma_f32_16x16x32_f16(akr[NBc][0], bqf[is1][0], s1, 0, 0, 0); \
    s1 = __builtin_amdgcn_mfma_f32_16x16x32_f16(akr[NBc][1], bqf[is1][1], s1, 0, 0, 0); \
    if ((T) + 2 < 64) {                                                       \
        const f16* kn_ = kp + (size_t)((T) + 2) * 4096;                       \
        akr[CBc][0] = *(const f16x8*)(kn_);                                   \
        akr[CBc][1] = *(const f16x8*)(kn_ + 512);                             \
    }                                                                         \
    {                                                                         \
        const f16* vt_ = vln + (size_t)((T) + 1) * 1024;                      \
        _Pragma("unroll")                                                     \
        for (int ct_ = 0; ct_ < 4; ++ct_) {                                   \
            vr[NBc][ct_]     = *(const f16x8*)(vt_ + (size_t)(cw + ct_) * 65536);       \
            vr[NBc][ct_ + 4] = *(const f16x8*)(vt_ + (size_t)(cw + ct_) * 65536 + 512); \
        }                                                                     \
    }                                                                         \
    {                                                                         \
        float p0 = __expf(s0[0] - m0), p1 = __expf(s0[1] - m0);               \
        float p2 = __expf(s0[2] - m0), p3 = __expf(s0[3] - m0);               \
        lp0 += (p0 + p1) + (p2 + p3);                                         \
        u32x2 pw = { pk2(p0, p1), pk2(p2, p3) };                              \
        *(u32x2*)(pbB + (NBc) * 8192 + wb0) = pw;                             \
    }                                                                         \
    {                                                                         \
        float q0 = __expf(s1[0] - m1), q1 = __expf(s1[1] - m1);               \
        float q2 = __expf(s1[2] - m1), q3 = __expf(s1[3] - m1);               \
        lp1 += (q0 + q1) + (q2 + q3);                                         \
        u32x2 pw = { pk2(q0, q1), pk2(q2, q3) };                              \
        *(u32x2*)(pbB + (NBc) * 8192 + wb1) = pw;                             \
    }                                                                         \
    __builtin_amdgcn_s_setprio(1);                                            \
    _Pragma("unroll")                                                         \
    for (int ct_ = 0; ct_ < 4; ++ct_)                                         \
        _Pragma("unroll")                                                     \
        for (int is_ = 0; is_ < 4; ++is_)                                     \
            acc[ct_][is_] = __builtin_amdgcn_mfma_f32_16x16x32_f16(           \
                vr[CBc][ct_], pbf[is_][0], acc[ct_][is_], 0, 0, 0);           \
    _Pragma("unroll")                                                         \
    for (int ct_ = 0; ct_ < 4; ++ct_)                                         \
        _Pragma("unroll")                                                     \
        for (int is_ = 0; is_ < 4; ++is_)                                     \
            acc[ct_][is_] = __builtin_amdgcn_mfma_f32_16x16x32_f16(           \
                vr[CBc][ct_ + 4], pbf[is_][1], acc[ct_][is_], 0, 0, 0);       \
    __builtin_amdgcn_s_setprio(0);                                            \
    LGKM_BARRIER();                                                           \
}

// ---------------------------------------------------------------------------
// Kernel B: attn (R8 structure) + amdgpu_waves_per_eu(2,2).
//  Persistent live set (acc 64 + vr 64 + akr 16 + bqf 32 = 176 VGPR) exceeded
//  the heuristic 128-VGPR allocation -> scratch spills in the hot loop.
//  Pinning 2 waves/EU (forced anyway by 512-thr block @ 1 block/CU) lets the
//  allocator take up to 256 VGPR, eliminating the spills.
// ---------------------------------------------------------------------------
__global__ __launch_bounds__(512) __attribute__((amdgpu_waves_per_eu(2, 2)))
void attn(
    const f16* __restrict__ qt, const f16* __restrict__ ktf,
    const f16* __restrict__ vf, const float* __restrict__ x,
    const float* __restrict__ gamma, float* __restrict__ out)
{
    __shared__ __align__(16) char Pb[2][8192];   // P: 64 i x 64 j f16, dbuf
    __shared__ float mxs[8][4][16];
    __shared__ float lss[8][4][16];

    const int tid  = threadIdx.x;
    const int w    = tid >> 6;                  // 0..7
    const int lane = tid & 63;
    const int l15  = lane & 15;
    const int quad = lane >> 4;
    const int jt   = w & 3;
    const int ish  = w >> 2;
    const int is0  = ish * 2, is1 = is0 + 1;

    const int lin  = blockIdx.x;                // 0..255
    const int b    = (lin & 7) >> 1;            // XCD-pinned batch
    const int iblk = ((lin >> 3) << 1) | (lin & 1);
    const int i0   = iblk * 64;

    const f16* kln = ktf + (size_t)b * (N_ * M_) + lane * 8;
    const f16* vln = vf  + (size_t)b * (C_ * N_) + lane * 8;

    f16x8 bqf[4][2];
    #pragma unroll
    for (int is = 0; is < 4; ++is)
        #pragma unroll
        for (int kh = 0; kh < 2; ++kh)
            bqf[is][kh] = *(const f16x8*)(qt + ((size_t)(b * N_ + i0 + is * 16 + l15)) * M_
                                          + kh * 32 + quad * 8);

    // ---------------- pass 1: rowmax, j-range split across waves ----------
    float mx[4];
    #pragma unroll
    for (int is = 0; is < 4; ++is) mx[is] = -3.0e38f;
    {
        const f16* kw = kln + (size_t)(w * 512) * 64;
        f16x8 akc[4][2];
        #pragma unroll
        for (int t = 0; t < 4; ++t)
            #pragma unroll
            for (int kh = 0; kh < 2; ++kh)
                akc[t][kh] = *(const f16x8*)(kw + t * 1024 + kh * 512);

        #pragma unroll 2
        for (int jj = 0; jj < 512; jj += 64) {
            f16x8 akn[4][2];
            if (jj + 64 < 512) {
                const f16* kn = kw + (size_t)(jj + 64) * 64;
                #pragma unroll
                for (int t = 0; t < 4; ++t)
                    #pragma unroll
                    for (int kh = 0; kh < 2; ++kh)
                        akn[t][kh] = *(const f16x8*)(kn + t * 1024 + kh * 512);
            }
            #pragma unroll
            for (int t = 0; t < 4; ++t) {
                #pragma unroll
                for (int is = 0; is < 4; ++is) {
                    f32x4 s = {};
                    s = __builtin_amdgcn_mfma_f32_16x16x32_f16(akc[t][0], bqf[is][0], s, 0, 0, 0);
                    s = __builtin_amdgcn_mfma_f32_16x16x32_f16(akc[t][1], bqf[is][1], s, 0, 0, 0);
                    mx[is] = fmaxf(mx[is], fmaxf(fmaxf(s[0], s[1]), fmaxf(s[2], s[3])));
                }
            }
            #pragma unroll
            for (int t = 0; t < 4; ++t)
                #pragma unroll
                for (int kh = 0; kh < 2; ++kh)
                    akc[t][kh] = akn[t][kh];
        }
    }
    #pragma unroll
    for (int is = 0; is < 4; ++is) {
        mx[is] = fmaxf(mx[is], __shfl_xor(mx[is], 16, 64));
        mx[is] = fmaxf(mx[is], __shfl_xor(mx[is], 32, 64));
    }
    if (lane < 16) {
        #pragma unroll
        for (int is = 0; is < 4; ++is) mxs[w][is][lane] = mx[is];
    }
    __syncthreads();
    float m0 = -3.0e38f, m1 = -3.0e38f;
    #pragma unroll
    for (int w2 = 0; w2 < 8; ++w2) {
        m0 = fmaxf(m0, mxs[w2][is0][l15]);
        m1 = fmaxf(m1, mxs[w2][is1][l15]);
    }

    // ---------------- pass 2: pipelined P -> LDS -> PV ---------------------
    f32x4 acc[4][4] = {};
    float lp0 = 0.f, lp1 = 0.f;

    char* pbB = (char*)&Pb[0][0];
    const int swz = (l15 & 7) << 4;
    const int wb0 = ((is0 * 16 + l15) * 128 + (jt * 16 + quad * 4) * 2) ^ swz;
    const int wb1 = wb0 + 2048;
    int rb[4][2];
    #pragma unroll
    for (int is = 0; is < 4; ++is)
        #pragma unroll
        for (int kh = 0; kh < 2; ++kh)
            rb[is][kh] = ((is * 16 + l15) * 128 + kh * 64 + quad * 16) ^ swz;

    const f16* kp = kln + (size_t)(jt * 16) * 64;
    const int cw = w * 4;

    f16x8 akr[2][2];
    f16x8 vr[2][8];

    akr[0][0] = *(const f16x8*)(kp);
    akr[0][1] = *(const f16x8*)(kp + 512);
    {
        f32x4 s0 = {}, s1 = {};
        s0 = __builtin_amdgcn_mfma_f32_16x16x32_f16(akr[0][0], bqf[is0][0], s0, 0, 0, 0);
        s0 = __builtin_amdgcn_mfma_f32_16x16x32_f16(akr[0][1], bqf[is0][1], s0, 0, 0, 0);
        s1 = __builtin_amdgcn_mfma_f32_16x16x32_f16(akr[0][0], bqf[is1][0], s1, 0, 0, 0);
        s1 = __builtin_amdgcn_mfma_f32_16x16x32_f16(akr[0][1], bqf[is1][1], s1, 0, 0, 0);
        float p0 = __expf(s0[0] - m0), p1 = __expf(s0[1] - m0);
        float p2 = __expf(s0[2] - m0), p3 = __expf(s0[3] - m0);
        lp0 += (p0 + p1) + (p2 + p3);
        u32x2 pw0 = { pk2(p0, p1), pk2(p2, p3) };
        *(u32x2*)(pbB + wb0) = pw0;
        float q0 = __expf(s1[0] - m1), q1 = __expf(s1[1] - m1);
        float q2 = __expf(s1[2] - m1), q3 = __expf(s1[3] - m1);
        lp1 += (q0 + q1) + (q2 + q3);
        u32x2 pw1 = { pk2(q0, q1), pk2(q2, q3) };
        *(u32x2*)(pbB + wb1) = pw1;
    }
    akr[1][0] = *(const f16x8*)(kp + 4096);
    akr[1][1] = *(const f16x8*)(kp + 4096 + 512);
    #pragma unroll
    for (int ct = 0; ct < 4; ++ct) {
        vr[0][ct]     = *(const f16x8*)(vln + (size_t)(cw + ct) * 65536);
        vr[0][ct + 4] = *(const f16x8*)(vln + (size_t)(cw + ct) * 65536 + 512);
    }
    __syncthreads();

    for (int tt = 0; tt < 62; tt += 2) {
        ATTN_BODY(tt,     0, 1);
        ATTN_BODY(tt + 1, 1, 0);
    }
    ATTN_BODY(62, 0, 1);

    // epilogue: PV(63) — P in buf1 (written at T=62), V in vr[1]
    {
        f16x8 pbf[4][2];
        #pragma unroll
        for (int is = 0; is < 4; ++is)
            #pragma unroll
            for (int kh = 0; kh < 2; ++kh)
                pbf[is][kh] = *(const f16x8*)(pbB + 8192 + rb[is][kh]);
        #pragma unroll
        for (int ct = 0; ct < 4; ++ct)
            #pragma unroll
            for (int is = 0; is < 4; ++is)
                acc[ct][is] = __builtin_amdgcn_mfma_f32_16x16x32_f16(vr[1][ct], pbf[is][0], acc[ct][is], 0, 0, 0);
        #pragma unroll
        for (int ct = 0; ct < 4; ++ct)
            #pragma unroll
            for (int is = 0; is < 4; ++is)
                acc[ct][is] = __builtin_amdgcn_mfma_f32_16x16x32_f16(vr[1][ct + 4], pbf[is][1], acc[ct][is], 0, 0, 0);
    }

    // ---------------- l combine + epilogue ---------------------------------
    lp0 += __shfl_xor(lp0, 16, 64);
    lp0 += __shfl_xor(lp0, 32, 64);
    lp1 += __shfl_xor(lp1, 16, 64);
    lp1 += __shfl_xor(lp1, 32, 64);
    if (lane < 16) { lss[w][is0][lane] = lp0; lss[w][is1][lane] = lp1; }
    __syncthreads();

    float linv[4];
    #pragma unroll
    for (int is = 0; is < 4; ++is) {
        const int wb = (is >> 1) * 4;
        float l = (lss[wb + 0][is][l15] + lss[wb + 1][is][l15])
                + (lss[wb + 2][is][l15] + lss[wb + 3][is][l15]);
        linv[is] = 1.0f / l;
    }

    const float g = gamma[0];
    #pragma unroll
    for (int is = 0; is < 4; ++is) {
        const int i = i0 + is * 16 + l15;
        #pragma unroll
        for (int ct = 0; ct < 4; ++ct) {
            #pragma unroll
            for (int r = 0; r < 4; ++r) {
                const int c = w * 64 + ct * 16 + quad * 4 + r;
                const size_t idx = ((size_t)(b * C_ + c)) * N_ + i;
                out[idx] = g * (acc[ct][is][r] * linv[is]) + x[idx];
            }
        }
    }
}

// ---------------------------------------------------------------------------
extern "C" void kernel_launch(void* const* d_in, const int* in_sizes, int n_in,
                              void* d_out, int out_size, void* d_ws, size_t ws_size,
                              hipStream_t stream)
{
    const float* x     = (const float*)d_in[0];
    const float* Wq    = (const float*)d_in[1];
    const float* bq    = (const float*)d_in[2];
    const float* Wk    = (const float*)d_in[3];
    const float* bk    = (const float*)d_in[4];
    const float* Wv    = (const float*)d_in[5];
    const float* bv    = (const float*)d_in[6];
    const float* gamma = (const float*)d_in[7];
    float* out = (float*)d_out;

    char* ws = (char*)d_ws;
    f16* qt  = (f16*)ws;                                   // B*N*M   ( 2 MB)
    f16* ktf = qt + (size_t)B_ * N_ * M_;                  // B*N*M   ( 2 MB)
    f16* vf  = ktf + (size_t)B_ * N_ * M_;                 // B*C*N   (16 MB)
    f16* Wf  = vf + (size_t)B_ * C_ * N_;                  // 640*512 (0.6 MB)

    wcvt<<<dim3(160), 256, 0, stream>>>(Wq, Wk, Wv, Wf);
    qkv5<<<dim3(N_ / 64, B_), 512, 0, stream>>>(Wf, x, bq, bk, bv, qt, ktf, vf);
    attn<<<dim3(256), 512, 0, stream>>>(qt, ktf, vf, x, gamma, out);
}

// Round 12
// 216.109 us; speedup vs baseline: 1.3049x; 1.0154x over previous
//
#include <hip/hip_runtime.h>

typedef _Float16 f16;
typedef _Float16 f16x8 __attribute__((ext_vector_type(8)));
typedef float    f32x4 __attribute__((ext_vector_type(4)));
typedef unsigned int u32x2 __attribute__((ext_vector_type(2)));

#define B_ 4
#define C_ 512
#define N_ 4096
#define M_ 64

// lgkm-only barrier, no memory clobber (clobber forces a vmcnt(0) drain).
#define LGKM_BARRIER()                                        \
    __builtin_amdgcn_sched_barrier(0);                        \
    asm volatile("s_waitcnt lgkmcnt(0)");                     \
    __builtin_amdgcn_s_barrier();                             \
    __builtin_amdgcn_sched_barrier(0);

__device__ __forceinline__ unsigned pk2(float a, float b) {
    union { f16 h[2]; unsigned u; } t;
    t.h[0] = (f16)a; t.h[1] = (f16)b;
    return t.u;
}

// ---------------------------------------------------------------------------
// Kernel W: convert [Wq;Wk;Wv] fp32 -> Wf[640][512] f16 (unchanged).
// ---------------------------------------------------------------------------
__global__ __launch_bounds__(256) void wcvt(
    const float* __restrict__ Wq, const float* __restrict__ Wk,
    const float* __restrict__ Wv, f16* __restrict__ Wf)
{
    const int e = (blockIdx.x * 256 + threadIdx.x) * 8;
    const float* src;
    int off;
    if (e < 32768)      { src = Wq; off = e; }
    else if (e < 65536) { src = Wk; off = e - 32768; }
    else                { src = Wv; off = e - 65536; }
    float4 a = *(const float4*)(src + off);
    float4 b = *(const float4*)(src + off + 4);
    f16x8 o;
    o[0]=(f16)a.x; o[1]=(f16)a.y; o[2]=(f16)a.z; o[3]=(f16)a.w;
    o[4]=(f16)b.x; o[5]=(f16)b.y; o[6]=(f16)b.z; o[7]=(f16)b.w;
    *(f16x8*)(Wf + e) = o;
}

// ---------------------------------------------------------------------------
// Kernel A (R9 "qkv5", unchanged — ran clean): single-barrier producer.
// ---------------------------------------------------------------------------
__global__ __launch_bounds__(512) __attribute__((amdgpu_waves_per_eu(2, 2)))
void qkv5(
    const f16* __restrict__ Wf, const float* __restrict__ x,
    const float* __restrict__ bq, const float* __restrict__ bk,
    const float* __restrict__ bv,
    f16* __restrict__ qt, f16* __restrict__ ktf, f16* __restrict__ vf)
{
    __shared__ __align__(16) char sX[65536];   // [64n][512c] f16, swizzled
    __shared__ float sBias[640];

    const int tid  = threadIdx.x;
    const int w    = tid >> 6;
    const int lane = tid & 63;
    const int l15  = lane & 15;
    const int quad = lane >> 4;
    const int n0   = blockIdx.x * 64;
    const int b    = blockIdx.y;
    const int row0 = w * 80;

    for (int e = tid; e < 640; e += 512)
        sBias[e] = (e < 64) ? bq[e] : (e < 128) ? bk[e - 64] : bv[e - 128];

    const float* xg = x + (size_t)b * (C_ * N_) + n0 + lane;
    #pragma unroll
    for (int s = 0; s < 8; ++s) {
        float g[8];
        #pragma unroll
        for (int u = 0; u < 8; ++u)
            g[u] = xg[(size_t)(s * 64 + w * 8 + u) * N_];
        f16x8 h;
        #pragma unroll
        for (int u = 0; u < 8; ++u) h[u] = (f16)g[u];
        const int c0 = s * 64 + w * 8;
        *(f16x8*)(sX + ((lane * 1024 + c0 * 2) ^ ((lane & 7) << 4))) = h;
    }
    __syncthreads();   // the ONLY barrier

    f32x4 acc[5][4] = {};
    const f16* wp = Wf + (size_t)row0 * 512 + quad * 8;

    #pragma unroll
    for (int t = 0; t < 8; ++t) {
        f16x8 af[5][2];
        #pragma unroll
        for (int ot = 0; ot < 5; ++ot)
            #pragma unroll
            for (int kh = 0; kh < 2; ++kh)
                af[ot][kh] = *(const f16x8*)(wp + (size_t)(ot * 16 + l15) * 512
                                             + t * 64 + kh * 32);
        f16x8 bf[4][2];
        #pragma unroll
        for (int nt = 0; nt < 4; ++nt)
            #pragma unroll
            for (int kh = 0; kh < 2; ++kh) {
                const int byte = ((nt * 16 + l15) * 1024 + t * 128 + kh * 64 + quad * 16)
                                 ^ ((l15 & 7) << 4);
                bf[nt][kh] = *(const f16x8*)(sX + byte);
            }

        #pragma unroll
        for (int ot = 0; ot < 5; ++ot)
            #pragma unroll
            for (int kh = 0; kh < 2; ++kh)
                #pragma unroll
                for (int nt = 0; nt < 4; ++nt)
                    acc[ot][nt] = __builtin_amdgcn_mfma_f32_16x16x32_f16(
                        af[ot][kh], bf[nt][kh], acc[ot][nt], 0, 0, 0);
    }

    #pragma unroll
    for (int ot = 0; ot < 5; ++ot) {
        const int rowBase = row0 + ot * 16;
        const int rq = rowBase + quad * 4;
        #pragma unroll
        for (int nt = 0; nt < 4; ++nt) {
            const int n = n0 + nt * 16 + l15;
            union { f16 h[4]; unsigned long long u; } pkv;
            #pragma unroll
            for (int r = 0; r < 4; ++r)
                pkv.h[r] = (f16)(acc[ot][nt][r] + sBias[rq + r]);
            if (rowBase < 64) {
                *(unsigned long long*)(qt + ((size_t)(b * N_ + n)) * M_ + rq) = pkv.u;
            } else if (rowBase < 128) {
                const int ol = rq - 64;
                size_t idx = (((size_t)b * 256 + (n >> 4)) * 2 + (ol >> 5)) * 512
                           + (size_t)((((ol >> 3) & 3) * 16 + (n & 15)) * 8) + (ol & 7);
                *(unsigned long long*)(ktf + idx) = pkv.u;
            } else {
                const int c = rq - 128;
                #pragma unroll
                for (int r = 0; r < 4; ++r) {
                    size_t idx = ((size_t)b * (C_ * N_)) + (size_t)((c + r) >> 4) * 65536
                               + (size_t)(n >> 6) * 1024 + (size_t)((n >> 5) & 1) * 512
                               + (size_t)((((n >> 3) & 3) * 16 + ((c + r) & 15)) * 8) + (n & 7);
                    vf[idx] = pkv.h[r];
                }
            }
        }
    }
}

// ---------------------------------------------------------------------------
// attn tile body (R8 shape, ONE change: V prefetch depth 1 -> 2).
//  Per tile T (CBc = T&1 literal, NBc = 1-CBc):
//   read P(T) from buf CBc; QK(T+1) with akr[NBc]; K(T+2)->akr[CBc];
//   exp -> write P(T+1) -> buf NBc; PV(T) with vr[CBc];
//   THEN V(T+2)->vr[CBc]  (slot just consumed; read again at PV(T+2),
//   same parity, one barrier in between); lgkm-only barrier.
// ---------------------------------------------------------------------------
#define ATTN_BODY(T, CBc, NBc) {                                              \
    f16x8 pbf[4][2];                                                          \
    _Pragma("unroll")                                                         \
    for (int is_ = 0; is_ < 4; ++is_)                                         \
        _Pragma("unroll")                                                     \
        for (int kh_ = 0; kh_ < 2; ++kh_)                                     \
            pbf[is_][kh_] = *(const f16x8*)(pbB + (CBc) * 8192 + rb[is_][kh_]); \
    f32x4 s0 = {}, s1 = {};                                                   \
    s0 = __builtin_amdgcn_mfma_f32_16x16x32_f16(akr[NBc][0], bqf[is0][0], s0, 0, 0, 0); \
    s0 = __builtin_amdgcn_mfma_f32_16x16x32_f16(akr[NBc][1], bqf[is0][1], s0, 0, 0, 0); \
    s1 = __builtin_amdgcn_mfma_f32_16x16x32_f16(akr[NBc][0], bqf[is1][0], s1, 0, 0, 0); \
    s1 = __builtin_amdgcn_mfma_f32_16x16x32_f16(akr[NBc][1], bqf[is1][1], s1, 0, 0, 0); \
    if ((T) + 2 < 64) {                                                       \
        const f16* kn_ = kp + (size_t)((T) + 2) * 4096;                       \
        akr[CBc][0] = *(const f16x8*)(kn_);                                   \
        akr[CBc][1] = *(const f16x8*)(kn_ + 512);                             \
    }                                                                         \
    {                                                                         \
        float p0 = __expf(s0[0] - m0), p1 = __expf(s0[1] - m0);               \
        float p2 = __expf(s0[2] - m0), p3 = __expf(s0[3] - m0);               \
        lp0 += (p0 + p1) + (p2 + p3);                                         \
        u32x2 pw = { pk2(p0, p1), pk2(p2, p3) };                              \
        *(u32x2*)(pbB + (NBc) * 8192 + wb0) = pw;                             \
    }                                                                         \
    {                                                                         \
        float q0 = __expf(s1[0] - m1), q1 = __expf(s1[1] - m1);               \
        float q2 = __expf(s1[2] - m1), q3 = __expf(s1[3] - m1);               \
        lp1 += (q0 + q1) + (q2 + q3);                                         \
        u32x2 pw = { pk2(q0, q1), pk2(q2, q3) };                              \
        *(u32x2*)(pbB + (NBc) * 8192 + wb1) = pw;                             \
    }                                                                         \
    __builtin_amdgcn_s_setprio(1);                                            \
    _Pragma("unroll")                                                         \
    for (int ct_ = 0; ct_ < 4; ++ct_)                                         \
        _Pragma("unroll")                                                     \
        for (int is_ = 0; is_ < 4; ++is_)                                     \
            acc[ct_][is_] = __builtin_amdgcn_mfma_f32_16x16x32_f16(           \
                vr[CBc][ct_], pbf[is_][0], acc[ct_][is_], 0, 0, 0);           \
    _Pragma("unroll")                                                         \
    for (int ct_ = 0; ct_ < 4; ++ct_)                                         \
        _Pragma("unroll")                                                     \
        for (int is_ = 0; is_ < 4; ++is_)                                     \
            acc[ct_][is_] = __builtin_amdgcn_mfma_f32_16x16x32_f16(           \
                vr[CBc][ct_ + 4], pbf[is_][1], acc[ct_][is_], 0, 0, 0);       \
    __builtin_amdgcn_s_setprio(0);                                            \
    if ((T) + 2 < 64) {                                                       \
        const f16* vt_ = vln + (size_t)((T) + 2) * 1024;                      \
        _Pragma("unroll")                                                     \
        for (int ct_ = 0; ct_ < 4; ++ct_) {                                   \
            vr[CBc][ct_]     = *(const f16x8*)(vt_ + (size_t)(cw + ct_) * 65536);       \
            vr[CBc][ct_ + 4] = *(const f16x8*)(vt_ + (size_t)(cw + ct_) * 65536 + 512); \
        }                                                                     \
    }                                                                         \
    LGKM_BARRIER();                                                           \
}

// ---------------------------------------------------------------------------
// Kernel B: attn (R8 structure, V prefetch 2 tiles deep).
// ---------------------------------------------------------------------------
__global__ __launch_bounds__(512) __attribute__((amdgpu_waves_per_eu(2, 2)))
void attn(
    const f16* __restrict__ qt, const f16* __restrict__ ktf,
    const f16* __restrict__ vf, const float* __restrict__ x,
    const float* __restrict__ gamma, float* __restrict__ out)
{
    __shared__ __align__(16) char Pb[2][8192];   // P: 64 i x 64 j f16, dbuf
    __shared__ float mxs[8][4][16];
    __shared__ float lss[8][4][16];

    const int tid  = threadIdx.x;
    const int w    = tid >> 6;                  // 0..7
    const int lane = tid & 63;
    const int l15  = lane & 15;
    const int quad = lane >> 4;
    const int jt   = w & 3;
    const int ish  = w >> 2;
    const int is0  = ish * 2, is1 = is0 + 1;

    const int lin  = blockIdx.x;                // 0..255
    const int b    = (lin & 7) >> 1;            // XCD-pinned batch
    const int iblk = ((lin >> 3) << 1) | (lin & 1);
    const int i0   = iblk * 64;

    const f16* kln = ktf + (size_t)b * (N_ * M_) + lane * 8;
    const f16* vln = vf  + (size_t)b * (C_ * N_) + lane * 8;

    f16x8 bqf[4][2];
    #pragma unroll
    for (int is = 0; is < 4; ++is)
        #pragma unroll
        for (int kh = 0; kh < 2; ++kh)
            bqf[is][kh] = *(const f16x8*)(qt + ((size_t)(b * N_ + i0 + is * 16 + l15)) * M_
                                          + kh * 32 + quad * 8);

    // ---------------- pass 1: rowmax, j-range split across waves ----------
    float mx[4];
    #pragma unroll
    for (int is = 0; is < 4; ++is) mx[is] = -3.0e38f;
    {
        const f16* kw = kln + (size_t)(w * 512) * 64;
        f16x8 akc[4][2];
        #pragma unroll
        for (int t = 0; t < 4; ++t)
            #pragma unroll
            for (int kh = 0; kh < 2; ++kh)
                akc[t][kh] = *(const f16x8*)(kw + t * 1024 + kh * 512);

        #pragma unroll 2
        for (int jj = 0; jj < 512; jj += 64) {
            f16x8 akn[4][2];
            if (jj + 64 < 512) {
                const f16* kn = kw + (size_t)(jj + 64) * 64;
                #pragma unroll
                for (int t = 0; t < 4; ++t)
                    #pragma unroll
                    for (int kh = 0; kh < 2; ++kh)
                        akn[t][kh] = *(const f16x8*)(kn + t * 1024 + kh * 512);
            }
            #pragma unroll
            for (int t = 0; t < 4; ++t) {
                #pragma unroll
                for (int is = 0; is < 4; ++is) {
                    f32x4 s = {};
                    s = __builtin_amdgcn_mfma_f32_16x16x32_f16(akc[t][0], bqf[is][0], s, 0, 0, 0);
                    s = __builtin_amdgcn_mfma_f32_16x16x32_f16(akc[t][1], bqf[is][1], s, 0, 0, 0);
                    mx[is] = fmaxf(mx[is], fmaxf(fmaxf(s[0], s[1]), fmaxf(s[2], s[3])));
                }
            }
            #pragma unroll
            for (int t = 0; t < 4; ++t)
                #pragma unroll
                for (int kh = 0; kh < 2; ++kh)
                    akc[t][kh] = akn[t][kh];
        }
    }
    #pragma unroll
    for (int is = 0; is < 4; ++is) {
        mx[is] = fmaxf(mx[is], __shfl_xor(mx[is], 16, 64));
        mx[is] = fmaxf(mx[is], __shfl_xor(mx[is], 32, 64));
    }
    if (lane < 16) {
        #pragma unroll
        for (int is = 0; is < 4; ++is) mxs[w][is][lane] = mx[is];
    }
    __syncthreads();
    float m0 = -3.0e38f, m1 = -3.0e38f;
    #pragma unroll
    for (int w2 = 0; w2 < 8; ++w2) {
        m0 = fmaxf(m0, mxs[w2][is0][l15]);
        m1 = fmaxf(m1, mxs[w2][is1][l15]);
    }

    // ---------------- pass 2: pipelined P -> LDS -> PV ---------------------
    f32x4 acc[4][4] = {};
    float lp0 = 0.f, lp1 = 0.f;

    char* pbB = (char*)&Pb[0][0];
    const int swz = (l15 & 7) << 4;
    const int wb0 = ((is0 * 16 + l15) * 128 + (jt * 16 + quad * 4) * 2) ^ swz;
    const int wb1 = wb0 + 2048;
    int rb[4][2];
    #pragma unroll
    for (int is = 0; is < 4; ++is)
        #pragma unroll
        for (int kh = 0; kh < 2; ++kh)
            rb[is][kh] = ((is * 16 + l15) * 128 + kh * 64 + quad * 16) ^ swz;

    const f16* kp = kln + (size_t)(jt * 16) * 64;
    const int cw = w * 4;

    f16x8 akr[2][2];
    f16x8 vr[2][8];

    // prologue: QK(0) -> buf0; K(1) -> akr[1]; V(0) -> vr[0]; V(1) -> vr[1]
    akr[0][0] = *(const f16x8*)(kp);
    akr[0][1] = *(const f16x8*)(kp + 512);
    {
        f32x4 s0 = {}, s1 = {};
        s0 = __builtin_amdgcn_mfma_f32_16x16x32_f16(akr[0][0], bqf[is0][0], s0, 0, 0, 0);
        s0 = __builtin_amdgcn_mfma_f32_16x16x32_f16(akr[0][1], bqf[is0][1], s0, 0, 0, 0);
        s1 = __builtin_amdgcn_mfma_f32_16x16x32_f16(akr[0][0], bqf[is1][0], s1, 0, 0, 0);
        s1 = __builtin_amdgcn_mfma_f32_16x16x32_f16(akr[0][1], bqf[is1][1], s1, 0, 0, 0);
        float p0 = __expf(s0[0] - m0), p1 = __expf(s0[1] - m0);
        float p2 = __expf(s0[2] - m0), p3 = __expf(s0[3] - m0);
        lp0 += (p0 + p1) + (p2 + p3);
        u32x2 pw0 = { pk2(p0, p1), pk2(p2, p3) };
        *(u32x2*)(pbB + wb0) = pw0;
        float q0 = __expf(s1[0] - m1), q1 = __expf(s1[1] - m1);
        float q2 = __expf(s1[2] - m1), q3 = __expf(s1[3] - m1);
        lp1 += (q0 + q1) + (q2 + q3);
        u32x2 pw1 = { pk2(q0, q1), pk2(q2, q3) };
        *(u32x2*)(pbB + wb1) = pw1;
    }
    akr[1][0] = *(const f16x8*)(kp + 4096);
    akr[1][1] = *(const f16x8*)(kp + 4096 + 512);
    #pragma unroll
    for (int ct = 0; ct < 4; ++ct) {
        vr[0][ct]     = *(const f16x8*)(vln + (size_t)(cw + ct) * 65536);
        vr[0][ct + 4] = *(const f16x8*)(vln + (size_t)(cw + ct) * 65536 + 512);
        vr[1][ct]     = *(const f16x8*)(vln + 1024 + (size_t)(cw + ct) * 65536);
        vr[1][ct + 4] = *(const f16x8*)(vln + 1024 + (size_t)(cw + ct) * 65536 + 512);
    }
    __syncthreads();

    for (int tt = 0; tt < 62; tt += 2) {
        ATTN_BODY(tt,     0, 1);
        ATTN_BODY(tt + 1, 1, 0);
    }
    ATTN_BODY(62, 0, 1);

    // epilogue: PV(63) — P in buf1 (written at T=62), V(63) in vr[1]
    // (loaded at body T=61, CBc=1).
    {
        f16x8 pbf[4][2];
        #pragma unroll
        for (int is = 0; is < 4; ++is)
            #pragma unroll
            for (int kh = 0; kh < 2; ++kh)
                pbf[is][kh] = *(const f16x8*)(pbB + 8192 + rb[is][kh]);
        #pragma unroll
        for (int ct = 0; ct < 4; ++ct)
            #pragma unroll
            for (int is = 0; is < 4; ++is)
                acc[ct][is] = __builtin_amdgcn_mfma_f32_16x16x32_f16(vr[1][ct], pbf[is][0], acc[ct][is], 0, 0, 0);
        #pragma unroll
        for (int ct = 0; ct < 4; ++ct)
            #pragma unroll
            for (int is = 0; is < 4; ++is)
                acc[ct][is] = __builtin_amdgcn_mfma_f32_16x16x32_f16(vr[1][ct + 4], pbf[is][1], acc[ct][is], 0, 0, 0);
    }

    // ---------------- l combine + epilogue ---------------------------------
    lp0 += __shfl_xor(lp0, 16, 64);
    lp0 += __shfl_xor(lp0, 32, 64);
    lp1 += __shfl_xor(lp1, 16, 64);
    lp1 += __shfl_xor(lp1, 32, 64);
    if (lane < 16) { lss[w][is0][lane] = lp0; lss[w][is1][lane] = lp1; }
    __syncthreads();

    float linv[4];
    #pragma unroll
    for (int is = 0; is < 4; ++is) {
        const int wb = (is >> 1) * 4;
        float l = (lss[wb + 0][is][l15] + lss[wb + 1][is][l15])
                + (lss[wb + 2][is][l15] + lss[wb + 3][is][l15]);
        linv[is] = 1.0f / l;
    }

    const float g = gamma[0];
    #pragma unroll
    for (int is = 0; is < 4; ++is) {
        const int i = i0 + is * 16 + l15;
        #pragma unroll
        for (int ct = 0; ct < 4; ++ct) {
            #pragma unroll
            for (int r = 0; r < 4; ++r) {
                const int c = w * 64 + ct * 16 + quad * 4 + r;
                const size_t idx = ((size_t)(b * C_ + c)) * N_ + i;
                out[idx] = g * (acc[ct][is][r] * linv[is]) + x[idx];
            }
        }
    }
}

// ---------------------------------------------------------------------------
extern "C" void kernel_launch(void* const* d_in, const int* in_sizes, int n_in,
                              void* d_out, int out_size, void* d_ws, size_t ws_size,
                              hipStream_t stream)
{
    const float* x     = (const float*)d_in[0];
    const float* Wq    = (const float*)d_in[1];
    const float* bq    = (const float*)d_in[2];
    const float* Wk    = (const float*)d_in[3];
    const float* bk    = (const float*)d_in[4];
    const float* Wv    = (const float*)d_in[5];
    const float* bv    = (const float*)d_in[6];
    const float* gamma = (const float*)d_in[7];
    float* out = (float*)d_out;

    char* ws = (char*)d_ws;
    f16* qt  = (f16*)ws;                                   // B*N*M   ( 2 MB)
    f16* ktf = qt + (size_t)B_ * N_ * M_;                  // B*N*M   ( 2 MB)
    f16* vf  = ktf + (size_t)B_ * N_ * M_;                 // B*C*N   (16 MB)
    f16* Wf  = vf + (size_t)B_ * C_ * N_;                  // 640*512 (0.6 MB)

    wcvt<<<dim3(160), 256, 0, stream>>>(Wq, Wk, Wv, Wf);
    qkv5<<<dim3(N_ / 64, B_), 512, 0, stream>>>(Wf, x, bq, bk, bv, qt, ktf, vf);
    attn<<<dim3(256), 512, 0, stream>>>(qt, ktf, vf, x, gamma, out);
}